// Round 4
// baseline (125.118 us; speedup 1.0000x reference)
//
#include <hip/hip_runtime.h>
#include <hip/hip_cooperative_groups.h>
#include <math.h>

#define TEMP_INV 0.2f
#define BIAS 0.0001f

namespace cg = cooperative_groups;

// One cooperative kernel:
//   Phase 1: s1[n]=ne[n].W[0:128], s2[n]=ne[n].W[128:256]  (+ srel, shq tables)
//   grid.sync()
//   Phase 2: per-edge Gumbel-sigmoid gate
__global__ __launch_bounds__(256) void fused_all_kernel(
        const float* __restrict__ ne,
        const float* __restrict__ R,
        const float* __restrict__ W,
        const float* __restrict__ bias_ptr,
        const int* __restrict__ h_index,
        const int* __restrict__ r_index,
        const int* __restrict__ rows,
        const int* __restrict__ cols,
        const int* __restrict__ etype,
        const int* __restrict__ bid,
        const float* __restrict__ eps_u,
        float* __restrict__ s1,
        float* __restrict__ s2,
        float* __restrict__ srel,
        float* __restrict__ shq,
        float* __restrict__ out,
        int n_nodes, int num_rel, int B, int E) {
    const int lane   = threadIdx.x & 63;
    const int l32    = lane & 31;
    const int half   = lane >> 5;                 // which node of the pair
    const int wid    = (blockIdx.x * blockDim.x + threadIdx.x) >> 6;
    const int nwaves = (gridDim.x * blockDim.x) >> 6;

    // ---------------- Phase 1: dots ----------------
    {
        const int npairs = (n_nodes + 1) >> 1;
        const int supers = (npairs + 3) >> 2;
        const int total  = supers + num_rel + B;

        const float4* W4 = (const float4*)W;
        const float4 w1 = W4[l32];        // W[0:128]
        const float4 w2 = W4[32 + l32];   // W[128:256]

        for (int t = wid; t < total; t += nwaves) {
            if (t < supers) {
                const int pair0 = t * 4;
                float4 e[4];
                int node[4];
                #pragma unroll
                for (int j = 0; j < 4; ++j) {
                    node[j] = (pair0 + j) * 2 + half;
                    e[j] = make_float4(0.f, 0.f, 0.f, 0.f);
                    if (node[j] < n_nodes)
                        e[j] = ((const float4*)(ne + (size_t)node[j] * 128))[l32];
                }
                #pragma unroll
                for (int j = 0; j < 4; ++j) {
                    const float p1 = e[j].x * w1.x + e[j].y * w1.y + e[j].z * w1.z + e[j].w * w1.w;
                    const float p2 = e[j].x * w2.x + e[j].y * w2.y + e[j].z * w2.z + e[j].w * w2.w;
                    const float q1 = __shfl_xor(p1, 16);
                    const float q2 = __shfl_xor(p2, 16);
                    float a = (l32 < 16) ? (p1 + q1) : (p2 + q2);
                    a += __shfl_xor(a, 8);
                    a += __shfl_xor(a, 4);
                    a += __shfl_xor(a, 2);
                    a += __shfl_xor(a, 1);
                    if (node[j] < n_nodes) {
                        if (l32 == 0)       s1[node[j]] = a;
                        else if (l32 == 16) s2[node[j]] = a;
                    }
                }
            } else if (t < supers + num_rel) {
                const int r = t - supers;
                const float2* W2 = (const float2*)W;
                const float2 w3 = W2[128 + lane];  // W[256:384]
                const float2 e  = ((const float2*)(R + (size_t)r * 128))[lane];
                float p = e.x * w3.x + e.y * w3.y;
                #pragma unroll
                for (int off = 32; off; off >>= 1) p += __shfl_xor(p, off);
                if (lane == 0) srel[r] = p;
            } else {
                const int bb = t - supers - num_rel;
                const float2* W2 = (const float2*)W;
                const float2 w4 = W2[192 + lane];  // W[384:512]
                const float2 w5 = W2[256 + lane];  // W[512:640]
                const float2 h  = ((const float2*)(ne + (size_t)h_index[bb] * 128))[lane];
                const float2 q  = ((const float2*)(R  + (size_t)r_index[bb] * 128))[lane];
                float p = h.x * w4.x + h.y * w4.y + q.x * w5.x + q.y * w5.y;
                #pragma unroll
                for (int off = 32; off; off >>= 1) p += __shfl_xor(p, off);
                if (lane == 0) shq[bb] = p + bias_ptr[0];
            }
        }
    }

    cg::this_grid().sync();

    // ---------------- Phase 2: edge gate, 2 edges/thread ----------------
    {
        const int tid      = blockIdx.x * blockDim.x + threadIdx.x;
        const int nthreads = gridDim.x * blockDim.x;
        const int npair_e  = E >> 1;          // E is even (500000)
        for (int p = tid; p < npair_e; p += nthreads) {
            const int2   r2 = ((const int2*)rows)[p];
            const int2   c2 = ((const int2*)cols)[p];
            const int2   t2 = ((const int2*)etype)[p];
            const int2   b2 = ((const int2*)bid)[p];
            const float2 u2 = ((const float2*)eps_u)[p];
            const float a0 = s1[r2.x],   a1 = s1[r2.y];
            const float c0 = s2[c2.x],   c1 = s2[c2.y];
            const float e0 = srel[t2.x], e1 = srel[t2.y];
            const float q0 = shq[b2.x],  q1 = shq[b2.y];

            const float eps0   = fmaf(u2.x, (2.0f * BIAS - 1.0f), (1.0f - BIAS));
            const float eps1   = fmaf(u2.y, (2.0f * BIAS - 1.0f), (1.0f - BIAS));
            const float logit0 = __logf(eps0) - __logf(1.0f - eps0);
            const float logit1 = __logf(eps1) - __logf(1.0f - eps1);
            const float g0 = (logit0 + a0 + c0 + e0 + q0) * TEMP_INV;
            const float g1 = (logit1 + a1 + c1 + e1 + q1) * TEMP_INV;
            float2 o;
            o.x = __builtin_amdgcn_rcpf(1.0f + __expf(-g0));
            o.y = __builtin_amdgcn_rcpf(1.0f + __expf(-g1));
            ((float2*)out)[p] = o;
        }
        // odd-tail guard (not hit for E=500000, kept for generality)
        if ((E & 1) && tid == 0) {
            const int i = E - 1;
            const float sw  = s1[rows[i]] + s2[cols[i]] + srel[etype[i]] + shq[bid[i]];
            const float eps = fmaf(eps_u[i], (2.0f * BIAS - 1.0f), (1.0f - BIAS));
            const float lg  = __logf(eps) - __logf(1.0f - eps);
            const float g   = (lg + sw) * TEMP_INV;
            out[i] = __builtin_amdgcn_rcpf(1.0f + __expf(-g));
        }
    }
}

extern "C" void kernel_launch(void* const* d_in, const int* in_sizes, int n_in,
                              void* d_out, int out_size, void* d_ws, size_t ws_size,
                              hipStream_t stream) {
    const float* node_embeds = (const float*)d_in[0];
    const float* R           = (const float*)d_in[1];
    const float* W           = (const float*)d_in[2];
    const float* b           = (const float*)d_in[3];
    const float* eps_u       = (const float*)d_in[4];
    const int*   edge_index  = (const int*)d_in[5];
    const int*   edge_type   = (const int*)d_in[6];
    const int*   batch_id    = (const int*)d_in[7];
    const int*   h_index     = (const int*)d_in[8];
    const int*   r_index     = (const int*)d_in[9];

    const int D       = 128;
    int n_nodes = in_sizes[0] / D;      // 200000
    int num_rel = in_sizes[1] / D;      // 200
    int E       = in_sizes[4];          // 500000
    int B       = in_sizes[8];          // 256

    const int* rows = edge_index;
    const int* cols = edge_index + E;

    // workspace layout: s1[N] | s2[N] | srel[num_rel] | shq[B]
    float* s1   = (float*)d_ws;
    float* s2   = s1 + n_nodes;
    float* srel = s2 + n_nodes;
    float* shq  = srel + num_rel;
    float* out  = (float*)d_out;

    void* args[] = {
        (void*)&node_embeds, (void*)&R, (void*)&W, (void*)&b,
        (void*)&h_index, (void*)&r_index,
        (void*)&rows, (void*)&cols, (void*)&edge_type, (void*)&batch_id,
        (void*)&eps_u,
        (void*)&s1, (void*)&s2, (void*)&srel, (void*)&shq,
        (void*)&out,
        (void*)&n_nodes, (void*)&num_rel, (void*)&B, (void*)&E,
    };
    // 1024 blocks x 256 thr = 4 blocks/CU — safely co-resident for coop launch.
    hipLaunchCooperativeKernel((const void*)fused_all_kernel,
                               dim3(1024), dim3(256), args, 0, stream);
}

// Round 5
// 54.478 us; speedup vs baseline: 2.2967x; 2.2967x over previous
//
#include <hip/hip_runtime.h>
#include <math.h>

#define TEMP_INV 0.2f
#define BIAS 0.0001f
#define MAGIC 0x5EEDBEA7u
#define GRID_BLOCKS 512
#define SPIN_CAP (1L << 26)   // anti-hang escape: fail visibly, don't hang harness

__device__ __forceinline__ unsigned ld_agent(const unsigned* p) {
    return __hip_atomic_load(p, __ATOMIC_RELAXED, __HIP_MEMORY_SCOPE_AGENT);
}
__device__ __forceinline__ void st_agent(unsigned* p, unsigned v) {
    __hip_atomic_store(p, v, __ATOMIC_RELAXED, __HIP_MEMORY_SCOPE_AGENT);
}

// Single normal-launch kernel:
//   Phase 1: s1[n]=ne[n].W[0:128], s2[n]=ne[n].W[128:256] (+ srel, shq tables)
//   hand-rolled device barrier (poison-proof MAGIC flags, self-cleaning)
//   Phase 2: per-edge Gumbel-sigmoid gate
__global__ __launch_bounds__(256) void fused_all_kernel(
        const float* __restrict__ ne,
        const float* __restrict__ R,
        const float* __restrict__ W,
        const float* __restrict__ bias_ptr,
        const int* __restrict__ h_index,
        const int* __restrict__ r_index,
        const int* __restrict__ rows,
        const int* __restrict__ cols,
        const int* __restrict__ etype,
        const int* __restrict__ bid,
        const float* __restrict__ eps_u,
        float* __restrict__ s1,
        float* __restrict__ s2,
        float* __restrict__ srel,
        float* __restrict__ shq,
        unsigned* __restrict__ flags_in,
        unsigned* __restrict__ flags_done,
        unsigned* __restrict__ go,
        float* __restrict__ out,
        int n_nodes, int num_rel, int B, int E) {
    const int lane   = threadIdx.x & 63;
    const int l32    = lane & 31;
    const int half   = lane >> 5;
    const int wid    = (blockIdx.x * blockDim.x + threadIdx.x) >> 6;
    const int nwaves = (gridDim.x * blockDim.x) >> 6;

    // ---------------- Phase 1: dots (R3 body) ----------------
    {
        const int npairs = (n_nodes + 1) >> 1;
        const int supers = (npairs + 3) >> 2;
        const int total  = supers + num_rel + B;

        const float4* W4 = (const float4*)W;
        const float4 w1 = W4[l32];        // W[0:128]
        const float4 w2 = W4[32 + l32];   // W[128:256]

        for (int t = wid; t < total; t += nwaves) {
            if (t < supers) {
                const int pair0 = t * 4;
                float4 e[4];
                int node[4];
                #pragma unroll
                for (int j = 0; j < 4; ++j) {
                    node[j] = (pair0 + j) * 2 + half;
                    e[j] = make_float4(0.f, 0.f, 0.f, 0.f);
                    if (node[j] < n_nodes)
                        e[j] = ((const float4*)(ne + (size_t)node[j] * 128))[l32];
                }
                #pragma unroll
                for (int j = 0; j < 4; ++j) {
                    const float p1 = e[j].x * w1.x + e[j].y * w1.y + e[j].z * w1.z + e[j].w * w1.w;
                    const float p2 = e[j].x * w2.x + e[j].y * w2.y + e[j].z * w2.z + e[j].w * w2.w;
                    const float q1 = __shfl_xor(p1, 16);
                    const float q2 = __shfl_xor(p2, 16);
                    float a = (l32 < 16) ? (p1 + q1) : (p2 + q2);
                    a += __shfl_xor(a, 8);
                    a += __shfl_xor(a, 4);
                    a += __shfl_xor(a, 2);
                    a += __shfl_xor(a, 1);
                    if (node[j] < n_nodes) {
                        if (l32 == 0)       s1[node[j]] = a;
                        else if (l32 == 16) s2[node[j]] = a;
                    }
                }
            } else if (t < supers + num_rel) {
                const int r = t - supers;
                const float2* W2 = (const float2*)W;
                const float2 w3 = W2[128 + lane];  // W[256:384]
                const float2 e  = ((const float2*)(R + (size_t)r * 128))[lane];
                float p = e.x * w3.x + e.y * w3.y;
                #pragma unroll
                for (int off = 32; off; off >>= 1) p += __shfl_xor(p, off);
                if (lane == 0) srel[r] = p;
            } else {
                const int bb = t - supers - num_rel;
                const float2* W2 = (const float2*)W;
                const float2 w4 = W2[192 + lane];  // W[384:512]
                const float2 w5 = W2[256 + lane];  // W[512:640]
                const float2 h  = ((const float2*)(ne + (size_t)h_index[bb] * 128))[lane];
                const float2 q  = ((const float2*)(R  + (size_t)r_index[bb] * 128))[lane];
                float p = h.x * w4.x + h.y * w4.y + q.x * w5.x + q.y * w5.y;
                #pragma unroll
                for (int off = 32; off; off >>= 1) p += __shfl_xor(p, off);
                if (lane == 0) shq[bb] = p + bias_ptr[0];
            }
        }
    }

    // ---------------- Device barrier (arrive) ----------------
    __syncthreads();
    if (threadIdx.x == 0) {
        __threadfence();                          // release s1/s2/srel/shq
        st_agent(&flags_in[blockIdx.x], MAGIC);
    }
    if (blockIdx.x == 0) {
        for (int s = threadIdx.x; s < GRID_BLOCKS; s += blockDim.x) {
            long guard = 0;
            while (ld_agent(&flags_in[s]) != MAGIC) {
                __builtin_amdgcn_s_sleep(2);
                if (++guard > SPIN_CAP) break;
            }
        }
        __syncthreads();
        if (threadIdx.x == 0) {
            __threadfence();
            st_agent(go, MAGIC);
        }
    }
    if (threadIdx.x == 0) {
        long guard = 0;
        while (ld_agent(go) != MAGIC) {
            __builtin_amdgcn_s_sleep(2);
            if (++guard > SPIN_CAP) break;
        }
        __threadfence();                          // acquire
    }
    __syncthreads();

    // ---------------- Phase 2: edge gate, 2 edges/thread (R3 body) ----------------
    {
        const int tid      = blockIdx.x * blockDim.x + threadIdx.x;
        const int nthreads = gridDim.x * blockDim.x;
        const int npair_e  = E >> 1;          // E even (500000)
        for (int p = tid; p < npair_e; p += nthreads) {
            const int2   r2 = ((const int2*)rows)[p];
            const int2   c2 = ((const int2*)cols)[p];
            const int2   t2 = ((const int2*)etype)[p];
            const int2   b2 = ((const int2*)bid)[p];
            const float2 u2 = ((const float2*)eps_u)[p];
            const float a0 = s1[r2.x],   a1 = s1[r2.y];
            const float c0 = s2[c2.x],   c1 = s2[c2.y];
            const float e0 = srel[t2.x], e1 = srel[t2.y];
            const float q0 = shq[b2.x],  q1 = shq[b2.y];

            const float eps0   = fmaf(u2.x, (2.0f * BIAS - 1.0f), (1.0f - BIAS));
            const float eps1   = fmaf(u2.y, (2.0f * BIAS - 1.0f), (1.0f - BIAS));
            const float logit0 = __logf(eps0) - __logf(1.0f - eps0);
            const float logit1 = __logf(eps1) - __logf(1.0f - eps1);
            const float g0 = (logit0 + a0 + c0 + e0 + q0) * TEMP_INV;
            const float g1 = (logit1 + a1 + c1 + e1 + q1) * TEMP_INV;
            float2 o;
            o.x = __builtin_amdgcn_rcpf(1.0f + __expf(-g0));
            o.y = __builtin_amdgcn_rcpf(1.0f + __expf(-g1));
            ((float2*)out)[p] = o;
        }
        if ((E & 1) && tid == 0) {
            const int i = E - 1;
            const float sw  = s1[rows[i]] + s2[cols[i]] + srel[etype[i]] + shq[bid[i]];
            const float eps = fmaf(eps_u[i], (2.0f * BIAS - 1.0f), (1.0f - BIAS));
            const float lg  = __logf(eps) - __logf(1.0f - eps);
            const float g   = (lg + sw) * TEMP_INV;
            out[i] = __builtin_amdgcn_rcpf(1.0f + __expf(-g));
        }
    }

    // ---------------- Cleanup: self-reset barrier state ----------------
    __syncthreads();
    if (threadIdx.x == 0) st_agent(&flags_done[blockIdx.x], MAGIC);
    if (blockIdx.x == 0) {
        for (int s = threadIdx.x; s < GRID_BLOCKS; s += blockDim.x) {
            long guard = 0;
            while (ld_agent(&flags_done[s]) != MAGIC) {
                __builtin_amdgcn_s_sleep(2);
                if (++guard > SPIN_CAP) break;
            }
        }
        __syncthreads();
        for (int s = threadIdx.x; s < GRID_BLOCKS; s += blockDim.x) {
            st_agent(&flags_in[s], 0u);
            st_agent(&flags_done[s], 0u);
        }
        if (threadIdx.x == 0) st_agent(go, 0u);
    }
}

extern "C" void kernel_launch(void* const* d_in, const int* in_sizes, int n_in,
                              void* d_out, int out_size, void* d_ws, size_t ws_size,
                              hipStream_t stream) {
    const float* node_embeds = (const float*)d_in[0];
    const float* R           = (const float*)d_in[1];
    const float* W           = (const float*)d_in[2];
    const float* b           = (const float*)d_in[3];
    const float* eps_u       = (const float*)d_in[4];
    const int*   edge_index  = (const int*)d_in[5];
    const int*   edge_type   = (const int*)d_in[6];
    const int*   batch_id    = (const int*)d_in[7];
    const int*   h_index     = (const int*)d_in[8];
    const int*   r_index     = (const int*)d_in[9];

    const int D       = 128;
    const int n_nodes = in_sizes[0] / D;      // 200000
    const int num_rel = in_sizes[1] / D;      // 200
    const int E       = in_sizes[4];          // 500000
    const int B       = in_sizes[8];          // 256

    const int* rows = edge_index;
    const int* cols = edge_index + E;

    // workspace: s1[N] | s2[N] | srel | shq | (align 256B) | flags_in[G] | flags_done[G] | go
    float* s1   = (float*)d_ws;
    float* s2   = s1 + n_nodes;
    float* srel = s2 + n_nodes;
    float* shq  = srel + num_rel;
    size_t tbl_bytes = (size_t)(2 * n_nodes + num_rel + B) * sizeof(float);
    tbl_bytes = (tbl_bytes + 255) & ~(size_t)255;
    unsigned* flags_in   = (unsigned*)((char*)d_ws + tbl_bytes);
    unsigned* flags_done = flags_in + GRID_BLOCKS;
    unsigned* go         = flags_done + GRID_BLOCKS;

    hipLaunchKernelGGL(fused_all_kernel, dim3(GRID_BLOCKS), dim3(256), 0, stream,
                       node_embeds, R, W, b, h_index, r_index,
                       rows, cols, edge_type, batch_id, eps_u,
                       s1, s2, srel, shq,
                       flags_in, flags_done, go,
                       (float*)d_out, n_nodes, num_rel, B, E);
}